// Round 5
// baseline (3638.712 us; speedup 1.0000x reference)
//
#include <hip/hip_runtime.h>
#include <stdint.h>

// ---------------------------------------------------------------------------
// SphereViT forward on gfx950.  Input dtype sniffed exactly via nl_ln1_g
// (all-ones: fp32 word 0x3F800000 vs bf16-pair 0x3F803F80).  Output written
// in the same dtype.  Residual fp32 in ws; all GEMMs bf16 MFMA 16x16x32.
// Evidence R1-R4: inputs are fp32 (bf16 misreads NaN'd); R3 failed only on
// bf16 output encoding.  WS = 88 MiB + flag; attn probs scratch in d_out.
// ---------------------------------------------------------------------------

typedef __attribute__((ext_vector_type(8))) short short8;   // 8 x bf16
typedef __attribute__((ext_vector_type(4))) float f32x4;    // MFMA C/D frag

#define EPS 1e-5f

__device__ __forceinline__ float b2f(ushort u) {
    union { uint32_t i; float f; } c; c.i = ((uint32_t)u) << 16; return c.f;
}
__device__ __forceinline__ ushort f2b(float f) {
    union { float f; uint32_t i; } c; c.f = f;
    uint32_t u = c.i;
    uint32_t r = (u + 0x7fffu + ((u >> 16) & 1u)) >> 16;   // RNE
    return (ushort)r;
}

// block-wide sum of (s, ss) for 256-thread blocks (4 waves)
__device__ __forceinline__ float2 block_sum2(float s, float ss, int tid) {
    #pragma unroll
    for (int o = 32; o; o >>= 1) { s += __shfl_xor(s, o); ss += __shfl_xor(ss, o); }
    __shared__ float ps[4], pss[4];
    int w = tid >> 6;
    if ((tid & 63) == 0) { ps[w] = s; pss[w] = ss; }
    __syncthreads();
    return make_float2(ps[0] + ps[1] + ps[2] + ps[3],
                       pss[0] + pss[1] + pss[2] + pss[3]);
}

// ---------------------------------------------------------------------------
// Exact dtype sniffer on the all-ones nl_ln1_g tensor.
// fp32 ones -> every u32 word == 0x3F800000; bf16 ones -> 0x3F803F80.
// Reads 256 words = 1024 B (safe: buffer is >=2048 B in either dtype).
// ---------------------------------------------------------------------------
__global__ void sniff_dtype(const uint32_t* __restrict__ ones, int* __restrict__ flag) {
    if (threadIdx.x == 0 && blockIdx.x == 0) {
        int c32 = 0, c16 = 0;
        for (int i = 0; i < 256; i++) {
            uint32_t w = ones[i];
            c32 += (w == 0x3F800000u);
            c16 += (w == 0x3F803F80u);
        }
        *flag = (c32 >= c16) ? 1 : 0;   // 1 -> inputs (and output) are fp32
    }
}

// ---------------------------------------------------------------------------
// NT GEMM: C[M,N] = A[M,K]*Bt[N,K]^T (+bias).  A,Bt bf16 (always from ws).
// 128x128 tile, BK=32, 4 waves (2x2 of 64x64), manual reg->LDS staging.
// MODE 0: store fp32 | 1: store bf16 | 2: fp32 +=
// ---------------------------------------------------------------------------
template <int MODE>
__global__ __launch_bounds__(256) void gemm_nt(
    const ushort* __restrict__ A, const ushort* __restrict__ Bt,
    const void* __restrict__ bias, int bias_off, const int* __restrict__ flagp,
    float* __restrict__ Cf, ushort* __restrict__ Cb,
    int M, int N, int K, int ldA, int ldB, int ldC)
{
    __shared__ ushort As[128 * 32];
    __shared__ ushort Bs[128 * 32];
    const int tid = threadIdx.x, lane = tid & 63, w = tid >> 6;
    const int m0 = blockIdx.y * 128, n0 = blockIdx.x * 128;
    const int wr = (w >> 1) * 64, wc = (w & 1) * 64;
    const int m16 = lane & 15, quad = lane >> 4;

    f32x4 acc[4][4];
    #pragma unroll
    for (int i = 0; i < 4; i++)
        #pragma unroll
        for (int j = 0; j < 4; j++) acc[i][j] = (f32x4){0.f, 0.f, 0.f, 0.f};

    for (int k0 = 0; k0 < K; k0 += 32) {
        uint4 av[2], bv[2];
        #pragma unroll
        for (int q = 0; q < 2; q++) {
            int idx = q * 256 + tid;            // 16B-chunk id 0..511
            int row = idx >> 2, ks = (idx & 3) * 8;
            av[q] = *(const uint4*)(A  + (size_t)(m0 + row) * ldA + k0 + ks);
            bv[q] = *(const uint4*)(Bt + (size_t)(n0 + row) * ldB + k0 + ks);
        }
        __syncthreads();                        // prev iter's readers done
        #pragma unroll
        for (int q = 0; q < 2; q++) {
            int idx = q * 256 + tid;
            *(uint4*)(As + idx * 8) = av[q];
            *(uint4*)(Bs + idx * 8) = bv[q];
        }
        __syncthreads();
        short8 a[4], b[4];
        #pragma unroll
        for (int t = 0; t < 4; t++)
            a[t] = *(const short8*)(As + (wr + t * 16 + m16) * 32 + quad * 8);
        #pragma unroll
        for (int t = 0; t < 4; t++)
            b[t] = *(const short8*)(Bs + (wc + t * 16 + m16) * 32 + quad * 8);
        #pragma unroll
        for (int i = 0; i < 4; i++)
            #pragma unroll
            for (int j = 0; j < 4; j++)
                acc[i][j] = __builtin_amdgcn_mfma_f32_16x16x32_bf16(a[i], b[j], acc[i][j], 0, 0, 0);
    }

    float bvals[4] = {0.f, 0.f, 0.f, 0.f};
    if (bias) {
        if (*flagp) {
            #pragma unroll
            for (int j = 0; j < 4; j++)
                bvals[j] = ((const float*)bias)[bias_off + n0 + wc + j * 16 + m16];
        } else {
            #pragma unroll
            for (int j = 0; j < 4; j++)
                bvals[j] = b2f(((const ushort*)bias)[bias_off + n0 + wc + j * 16 + m16]);
        }
    }
    #pragma unroll
    for (int i = 0; i < 4; i++)
        #pragma unroll
        for (int j = 0; j < 4; j++)
            #pragma unroll
            for (int r = 0; r < 4; r++) {
                int row = m0 + wr + i * 16 + quad * 4 + r;
                int col = n0 + wc + j * 16 + m16;
                float v = acc[i][j][r] + bvals[j];
                if (MODE == 0)      Cf[(size_t)row * ldC + col] = v;
                else if (MODE == 1) Cb[(size_t)row * ldC + col] = f2b(v);
                else                Cf[(size_t)row * ldC + col] += v;
            }
}

// ---------------------------------------------------------------------------
// Transpose W[K,N] -> Wt[N,K] bf16, reading fp32 or bf16 source.
// ---------------------------------------------------------------------------
__global__ __launch_bounds__(256) void transpose_k(
    const void* __restrict__ W, size_t eoff, ushort* __restrict__ Wt,
    int K, int N, const int* __restrict__ flagp)
{
    __shared__ ushort t[32][33];
    int f32 = *flagp;
    int n0 = blockIdx.x * 32, k0 = blockIdx.y * 32;
    int tx = threadIdx.x & 31, ty = threadIdx.x >> 5;
    if (f32) {
        const float* Wf = (const float*)W + eoff;
        #pragma unroll
        for (int i = ty; i < 32; i += 8) t[i][tx] = f2b(Wf[(size_t)(k0 + i) * N + n0 + tx]);
    } else {
        const ushort* Wb = (const ushort*)W + eoff;
        #pragma unroll
        for (int i = ty; i < 32; i += 8) t[i][tx] = Wb[(size_t)(k0 + i) * N + n0 + tx];
    }
    __syncthreads();
    #pragma unroll
    for (int i = ty; i < 32; i += 8) Wt[(size_t)(n0 + i) * K + k0 + tx] = t[tx][i];
}

// Dtype-convert copy (8 elems/thread), for conv_w (already [N,K] layout).
__global__ __launch_bounds__(256) void convert_copy(
    const void* __restrict__ src, ushort* __restrict__ dst,
    const int* __restrict__ flagp)
{
    size_t i = ((size_t)blockIdx.x * 256 + threadIdx.x) * 8;
    if (*flagp) {
        const float* s = (const float*)src + i;
        ushort t[8];
        #pragma unroll
        for (int x = 0; x < 8; x++) t[x] = f2b(s[x]);
        *(uint4*)(dst + i) = *(uint4*)t;
    } else {
        *(uint4*)(dst + i) = *(const uint4*)((const ushort*)src + i);
    }
}

// ---------------------------------------------------------------------------
// Patch gather: img[b,c,256,512] -> A[(b,h,w)][(c,p,q)] bf16 (4096x3072)
// ---------------------------------------------------------------------------
__global__ __launch_bounds__(256) void patch_gather(
    const void* __restrict__ img, ushort* __restrict__ Ap,
    const int* __restrict__ flagp)
{
    int t = blockIdx.x * 256 + threadIdx.x;
    int qc = t & 3;
    int p  = (t >> 2) & 31;
    int c  = (t >> 7) % 3;
    int rest = t / 384;
    int wg = rest & 15;
    int hg = (rest >> 4) & 7;
    int b  = rest >> 7;
    size_t si = ((size_t)((b * 3 + c) * 256 + hg * 32 + p)) * 512 + wg * 32 + qc * 8;
    size_t di = ((size_t)((b * 8 + hg) * 16 + wg)) * 3072 + c * 1024 + p * 32 + qc * 8;
    if (*flagp) {
        const float* s = (const float*)img + si;
        ushort tmp[8];
        #pragma unroll
        for (int x = 0; x < 8; x++) tmp[x] = f2b(s[x]);
        *(uint4*)(Ap + di) = *(uint4*)tmp;
    } else {
        *(uint4*)(Ap + di) = *(const uint4*)((const ushort*)img + si);
    }
}

// ---------------------------------------------------------------------------
// LayerNorm over 1024 (fp32 in) -> bf16 out.  g/b dual-dtype, +elem offset.
// ---------------------------------------------------------------------------
__global__ __launch_bounds__(256) void ln_f32_to_bf16(
    const float* __restrict__ X, const void* __restrict__ g,
    const void* __restrict__ b, int goff, const int* __restrict__ flagp,
    ushort* __restrict__ Y)
{
    int row = blockIdx.x, tid = threadIdx.x;
    float4 v = ((const float4*)(X + (size_t)row * 1024))[tid];
    float s = v.x + v.y + v.z + v.w;
    float ss = v.x * v.x + v.y * v.y + v.z * v.z + v.w * v.w;
    float2 r = block_sum2(s, ss, tid);
    float mu = r.x * (1.f / 1024.f);
    float var = fmaxf(r.y * (1.f / 1024.f) - mu * mu, 0.f);
    float rs = rsqrtf(var + EPS);
    int c0 = tid * 4;
    float gv[4], bv[4];
    if (*flagp) {
        #pragma unroll
        for (int x = 0; x < 4; x++) { gv[x] = ((const float*)g)[goff + c0 + x]; bv[x] = ((const float*)b)[goff + c0 + x]; }
    } else {
        #pragma unroll
        for (int x = 0; x < 4; x++) { gv[x] = b2f(((const ushort*)g)[goff + c0 + x]); bv[x] = b2f(((const ushort*)b)[goff + c0 + x]); }
    }
    ushort4 o4;
    o4.x = f2b((v.x - mu) * rs * gv[0] + bv[0]);
    o4.y = f2b((v.y - mu) * rs * gv[1] + bv[1]);
    o4.z = f2b((v.z - mu) * rs * gv[2] + bv[2]);
    o4.w = f2b((v.w - mu) * rs * gv[3] + bv[3]);
    *(ushort4*)(Y + (size_t)row * 1024 + c0) = o4;
}

// LN over 1024 in-place fp32, then add spherical positional embedding
__global__ __launch_bounds__(256) void ln2_pos(
    float* __restrict__ X, const void* __restrict__ g, const void* __restrict__ b,
    const void* __restrict__ sph_pos, const void* __restrict__ pos_w,
    const void* __restrict__ pos_b, const int* __restrict__ flagp)
{
    int f32 = *flagp;
    int row = blockIdx.x, tid = threadIdx.x;
    float4 v = ((const float4*)(X + (size_t)row * 1024))[tid];
    float s = v.x + v.y + v.z + v.w;
    float ss = v.x * v.x + v.y * v.y + v.z * v.z + v.w * v.w;
    float2 r = block_sum2(s, ss, tid);
    float mu = r.x * (1.f / 1024.f);
    float var = fmaxf(r.y * (1.f / 1024.f) - mu * mu, 0.f);
    float rs = rsqrtf(var + EPS);
    int n = row & 127;
    int c0 = tid * 4;
    float s0, s1, gv[4], bv[4], w0[4], w1[4], pb[4];
    if (f32) {
        s0 = ((const float*)sph_pos)[n * 2 + 0]; s1 = ((const float*)sph_pos)[n * 2 + 1];
        #pragma unroll
        for (int x = 0; x < 4; x++) {
            gv[x] = ((const float*)g)[c0 + x];  bv[x] = ((const float*)b)[c0 + x];
            w0[x] = ((const float*)pos_w)[c0 + x]; w1[x] = ((const float*)pos_w)[1024 + c0 + x];
            pb[x] = ((const float*)pos_b)[c0 + x];
        }
    } else {
        s0 = b2f(((const ushort*)sph_pos)[n * 2 + 0]); s1 = b2f(((const ushort*)sph_pos)[n * 2 + 1]);
        #pragma unroll
        for (int x = 0; x < 4; x++) {
            gv[x] = b2f(((const ushort*)g)[c0 + x]);  bv[x] = b2f(((const ushort*)b)[c0 + x]);
            w0[x] = b2f(((const ushort*)pos_w)[c0 + x]); w1[x] = b2f(((const ushort*)pos_w)[1024 + c0 + x]);
            pb[x] = b2f(((const ushort*)pos_b)[c0 + x]);
        }
    }
    float4 o;
    o.x = (v.x - mu) * rs * gv[0] + bv[0] + s0 * w0[0] + s1 * w1[0] + pb[0];
    o.y = (v.y - mu) * rs * gv[1] + bv[1] + s0 * w0[1] + s1 * w1[1] + pb[1];
    o.z = (v.z - mu) * rs * gv[2] + bv[2] + s0 * w0[2] + s1 * w1[2] + pb[2];
    o.w = (v.w - mu) * rs * gv[3] + bv[3] + s0 * w0[3] + s1 * w1[3] + pb[3];
    *(float4*)(X + (size_t)row * 1024 + c0) = o;
}

// ---------------------------------------------------------------------------
// QK^T per (b,h): dots = scale*(q.k)*(1+sph_dist)  (fp32 out)
// ---------------------------------------------------------------------------
__global__ __launch_bounds__(256) void attn_qk(
    const ushort* __restrict__ qkv, const void* __restrict__ sph_dist,
    const int* __restrict__ flagp, float* __restrict__ dots)
{
    __shared__ ushort Qs[128 * 64];
    __shared__ ushort Ks[128 * 64];
    int bh = blockIdx.x, b = bh >> 4, h = bh & 15;
    int tid = threadIdx.x;
    {
        int i = tid >> 1, half = (tid & 1) * 32;
        const ushort* qsrc = qkv + (size_t)(b * 128 + i) * 3072 + h * 64 + half;
        const ushort* ksrc = qsrc + 1024;
        uint4* qdst = (uint4*)(Qs + i * 64 + half);
        uint4* kdst = (uint4*)(Ks + i * 64 + half);
        #pragma unroll
        for (int x = 0; x < 4; x++) { qdst[x] = ((const uint4*)qsrc)[x]; kdst[x] = ((const uint4*)ksrc)[x]; }
    }
    __syncthreads();
    int lane = tid & 63, w = tid >> 6, m16 = lane & 15, quad = lane >> 4;
    f32x4 acc[2][8];
    #pragma unroll
    for (int i = 0; i < 2; i++)
        #pragma unroll
        for (int j = 0; j < 8; j++) acc[i][j] = (f32x4){0.f, 0.f, 0.f, 0.f};
    #pragma unroll
    for (int kq = 0; kq < 2; kq++) {
        short8 a[2], bb[8];
        #pragma unroll
        for (int rt = 0; rt < 2; rt++)
            a[rt] = *(const short8*)(Qs + (w * 32 + rt * 16 + m16) * 64 + kq * 32 + quad * 8);
        #pragma unroll
        for (int ct = 0; ct < 8; ct++)
            bb[ct] = *(const short8*)(Ks + (ct * 16 + m16) * 64 + kq * 32 + quad * 8);
        #pragma unroll
        for (int rt = 0; rt < 2; rt++)
            #pragma unroll
            for (int ct = 0; ct < 8; ct++)
                acc[rt][ct] = __builtin_amdgcn_mfma_f32_16x16x32_bf16(a[rt], bb[ct], acc[rt][ct], 0, 0, 0);
    }
    const float scale = 0.125f;
    int f32 = *flagp;
    #pragma unroll
    for (int rt = 0; rt < 2; rt++)
        #pragma unroll
        for (int ct = 0; ct < 8; ct++)
            #pragma unroll
            for (int r = 0; r < 4; r++) {
                int i = w * 32 + rt * 16 + quad * 4 + r;
                int j = ct * 16 + m16;
                float sd = f32 ? ((const float*)sph_dist)[i * 128 + j]
                               : b2f(((const ushort*)sph_dist)[i * 128 + j]);
                dots[((size_t)bh * 128 + i) * 128 + j] = acc[rt][ct][r] * scale * (1.f + sd);
            }
}

// ---------------------------------------------------------------------------
// Cross-head standardization + softmax.  One wave per (b,i); lane j, j+64.
// ---------------------------------------------------------------------------
__global__ __launch_bounds__(256) void attn_stats(
    const float* __restrict__ dots, ushort* __restrict__ attn)
{
    int gi = blockIdx.x * 4 + (threadIdx.x >> 6);
    int lane = threadIdx.x & 63;
    int b = gi >> 7, i = gi & 127;
    float v0[16], v1[16];
    #pragma unroll
    for (int h = 0; h < 16; h++) {
        const float* p = dots + ((size_t)(b * 16 + h) * 128 + i) * 128;
        v0[h] = p[lane]; v1[h] = p[lane + 64];
    }
    float s0 = 0.f, s1 = 0.f;
    #pragma unroll
    for (int h = 0; h < 16; h++) { s0 += v0[h]; s1 += v1[h]; }
    float mu0 = s0 * (1.f / 16.f), mu1 = s1 * (1.f / 16.f);
    float q0 = 0.f, q1 = 0.f;
    #pragma unroll
    for (int h = 0; h < 16; h++) {
        float d0 = v0[h] - mu0, d1 = v1[h] - mu1;
        q0 += d0 * d0; q1 += d1 * d1;
    }
    float r0 = rsqrtf(fmaxf(q0 * (1.f / 15.f), 1e-20f));   // ddof=1
    float r1 = rsqrtf(fmaxf(q1 * (1.f / 15.f), 1e-20f));
    #pragma unroll
    for (int h = 0; h < 16; h++) { v0[h] = (v0[h] - mu0) * r0; v1[h] = (v1[h] - mu1) * r1; }
    #pragma unroll
    for (int h = 0; h < 16; h++) {
        float m = fmaxf(v0[h], v1[h]);
        #pragma unroll
        for (int o = 32; o; o >>= 1) m = fmaxf(m, __shfl_xor(m, o));
        float e0 = __expf(v0[h] - m), e1 = __expf(v1[h] - m);
        float s = e0 + e1;
        #pragma unroll
        for (int o = 32; o; o >>= 1) s += __shfl_xor(s, o);
        float inv = 1.f / s;
        ushort* op = attn + ((size_t)(b * 16 + h) * 128 + i) * 128;
        op[lane] = f2b(e0 * inv);
        op[lane + 64] = f2b(e1 * inv);
    }
}

// ---------------------------------------------------------------------------
// PV per (b,h): o[i,d] = sum_j attn[i,j]*v[j,d] -> token-major bf16
// ---------------------------------------------------------------------------
__global__ __launch_bounds__(256) void attn_pv(
    const ushort* __restrict__ attn, const ushort* __restrict__ qkv,
    ushort* __restrict__ o)
{
    __shared__ ushort Ps[128 * 128];
    __shared__ ushort Vt[64 * 128];
    int bh = blockIdx.x, b = bh >> 4, h = bh & 15;
    int tid = threadIdx.x;
    {
        int i = tid >> 1, jh = (tid & 1) * 64;
        const uint4* src = (const uint4*)(attn + ((size_t)bh * 128 + i) * 128 + jh);
        uint4* dst = (uint4*)(Ps + i * 128 + jh);
        #pragma unroll
        for (int x = 0; x < 8; x++) dst[x] = src[x];
    }
    {
        int j = tid >> 1, dh = (tid & 1) * 32;
        const ushort* src = qkv + (size_t)(b * 128 + j) * 3072 + 2048 + h * 64 + dh;
        ushort tmp[32];
        #pragma unroll
        for (int x = 0; x < 4; x++) *(uint4*)(tmp + x * 8) = ((const uint4*)src)[x];
        #pragma unroll
        for (int x = 0; x < 32; x++) Vt[(dh + x) * 128 + j] = tmp[x];
    }
    __syncthreads();
    int lane = tid & 63, w = tid >> 6, m16 = lane & 15, quad = lane >> 4;
    f32x4 acc[2][4];
    #pragma unroll
    for (int i = 0; i < 2; i++)
        #pragma unroll
        for (int j = 0; j < 4; j++) acc[i][j] = (f32x4){0.f, 0.f, 0.f, 0.f};
    #pragma unroll
    for (int kq = 0; kq < 4; kq++) {
        short8 a[2], bb[4];
        #pragma unroll
        for (int rt = 0; rt < 2; rt++)
            a[rt] = *(const short8*)(Ps + (w * 32 + rt * 16 + m16) * 128 + kq * 32 + quad * 8);
        #pragma unroll
        for (int ct = 0; ct < 4; ct++)
            bb[ct] = *(const short8*)(Vt + (ct * 16 + m16) * 128 + kq * 32 + quad * 8);
        #pragma unroll
        for (int rt = 0; rt < 2; rt++)
            #pragma unroll
            for (int ct = 0; ct < 4; ct++)
                acc[rt][ct] = __builtin_amdgcn_mfma_f32_16x16x32_bf16(a[rt], bb[ct], acc[rt][ct], 0, 0, 0);
    }
    #pragma unroll
    for (int rt = 0; rt < 2; rt++)
        #pragma unroll
        for (int ct = 0; ct < 4; ct++)
            #pragma unroll
            for (int r = 0; r < 4; r++) {
                int i = w * 32 + rt * 16 + quad * 4 + r;
                int d = ct * 16 + m16;
                o[(size_t)(b * 128 + i) * 1024 + h * 64 + d] = f2b(acc[rt][ct][r]);
            }
}

// ---------------------------------------------------------------------------
// Final LN over 3072 (bf16 in) + un-patchify; writes fp32 OR bf16 per flag.
// ---------------------------------------------------------------------------
__global__ __launch_bounds__(256) void out_ln_rearrange(
    const ushort* __restrict__ Y, const void* __restrict__ g,
    const void* __restrict__ bb, const int* __restrict__ flagp,
    void* __restrict__ out)
{
    __shared__ float rowbuf[3072];
    int f32 = *flagp;
    int r = blockIdx.x;
    int b = r >> 7, n = r & 127, hg = n >> 4, wg = n & 15;
    int tid = threadIdx.x;
    float s = 0.f, ss = 0.f;
    #pragma unroll
    for (int x = 0; x < 3; x++) {
        ushort4 u = *(const ushort4*)(Y + (size_t)r * 3072 + (size_t)(x * 256 + tid) * 4);
        float4 v = make_float4(b2f(u.x), b2f(u.y), b2f(u.z), b2f(u.w));
        *(float4*)(rowbuf + (x * 256 + tid) * 4) = v;
        s += v.x + v.y + v.z + v.w;
        ss += v.x * v.x + v.y * v.y + v.z * v.z + v.w * v.w;
    }
    float2 red = block_sum2(s, ss, tid);   // barrier makes rowbuf visible
    float mu = red.x * (1.f / 3072.f);
    float var = fmaxf(red.y * (1.f / 3072.f) - mu * mu, 0.f);
    float rs = rsqrtf(var + EPS);
    int p1 = tid >> 3, sj = tid & 7;
    #pragma unroll
    for (int c = 0; c < 3; c++) {
        float vals[4];
        #pragma unroll
        for (int x = 0; x < 4; x++) {
            int p2 = sj * 4 + x;
            int col = p1 * 96 + p2 * 3 + c;
            float gv, bv;
            if (f32) { gv = ((const float*)g)[col];  bv = ((const float*)bb)[col]; }
            else     { gv = b2f(((const ushort*)g)[col]); bv = b2f(((const ushort*)bb)[col]); }
            vals[x] = (rowbuf[col] - mu) * rs * gv + bv;
        }
        size_t di = (size_t)((b * 3 + c) * 256 + hg * 32 + p1) * 512 + wg * 32 + sj * 4;
        if (f32) {
            *(float4*)((float*)out + di) = make_float4(vals[0], vals[1], vals[2], vals[3]);
        } else {
            ushort4 o4;
            #pragma unroll
            for (int x = 0; x < 4; x++) ((ushort*)&o4)[x] = f2b(vals[x]);
            *(ushort4*)((ushort*)out + di) = o4;
        }
    }
}

// ---------------------------------------------------------------------------
// Host-side orchestration
// ---------------------------------------------------------------------------
extern "C" void kernel_launch(void* const* d_in, const int* in_sizes, int n_in,
                              void* d_out, int out_size, void* d_ws, size_t ws_size,
                              hipStream_t stream)
{
    const void* img      = d_in[0];
    const void* sph_pos  = d_in[1];
    const void* sph_dist = d_in[2];
    const void* conv_w   = d_in[3];   // [1024,3072] = [N,K] already
    const void* conv_b   = d_in[4];
    const void* nl1g     = d_in[5];   // all-ones -> dtype sniff target
    const void* nl1b     = d_in[6];
    const void* nl_w     = d_in[7];
    const void* nl_b     = d_in[8];
    const void* nl2g     = d_in[9];
    const void* nl2b     = d_in[10];
    const void* pos_w    = d_in[11];
    const void* pos_b    = d_in[12];
    const void* ln_g     = d_in[13];
    const void* ln_b     = d_in[14];
    const void* wqkv     = d_in[15];
    const void* wo       = d_in[16];
    const void* wo_b     = d_in[17];
    const void* trg      = d_in[18];
    const void* trb      = d_in[19];
    const void* exp_w    = d_in[20];
    const void* exp_b    = d_in[21];
    const void* og       = d_in[22];
    const void* ob       = d_in[23];

    // --- workspace layout: 88 MiB + flag ---
    char* ws = (char*)d_ws;
    float*  xf    = (float*) (ws + 0);            // [0,16M)   fp32 residual [4096,1024]
    ushort* xb    = (ushort*)(ws + 16777216);     // [16,24M)  bf16 LN out [4096,1024]
    ushort* qkvb  = (ushort*)(ws + 25165824);     // [24,48M)  bf16 qkv / patch-mat / expand-out
    float*  dots  = (float*) (ws + 50331648);     // [48,80M)  fp32 dots [32,16,128,128]
    float*  y1    = (float*) (ws + 50331648);     //   overlay: fp32 patch-embed out (pre-loop)
    ushort* o_bf  = (ushort*)(ws + 50331648);     //   overlay: bf16 attn out (after dots dead)
    ushort* wTa   = (ushort*)(ws + 83886080);     // [80,86M)  weight^T [3072,1024]
    ushort* wTb   = (ushort*)(ws + 90177536);     // [86,88M)  weight^T [1024,1024]
    int*    flagp = (int*)   (ws + 92274688);     // dtype flag (1 = fp32 world)
    ushort* attnb = (ushort*)d_out;               // bf16 attn probs (16M; d_out dead until final write)

    sniff_dtype<<<1, 64, 0, stream>>>((const uint32_t*)nl1g, flagp);

    // patch embedding (patch matrix staged in qkvb region)
    patch_gather<<<6144, 256, 0, stream>>>(img, qkvb, flagp);
    convert_copy<<<1536, 256, 0, stream>>>(conv_w, wTa, flagp);   // 1024x3072 -> bf16
    gemm_nt<0><<<dim3(8, 32), 256, 0, stream>>>(qkvb, wTa, conv_b, 0, flagp, y1, nullptr,
                                                4096, 1024, 3072, 3072, 3072, 1024);
    // norm_linear
    ln_f32_to_bf16<<<4096, 256, 0, stream>>>(y1, nl1g, nl1b, 0, flagp, xb);
    transpose_k<<<dim3(32, 32), 256, 0, stream>>>(nl_w, 0, wTb, 1024, 1024, flagp);
    gemm_nt<0><<<dim3(8, 32), 256, 0, stream>>>(xb, wTb, nl_b, 0, flagp, xf, nullptr,
                                                4096, 1024, 1024, 1024, 1024, 1024);
    ln2_pos<<<4096, 256, 0, stream>>>(xf, nl2g, nl2b, sph_pos, pos_w, pos_b, flagp);

    // transformer blocks
    for (int l = 0; l < 12; l++) {
        transpose_k<<<dim3(96, 32), 256, 0, stream>>>(wqkv, (size_t)l * 1024 * 3072, wTa, 1024, 3072, flagp);
        transpose_k<<<dim3(32, 32), 256, 0, stream>>>(wo, (size_t)l * 1024 * 1024, wTb, 1024, 1024, flagp);
        ln_f32_to_bf16<<<4096, 256, 0, stream>>>(xf, ln_g, ln_b, l * 1024, flagp, xb);
        gemm_nt<1><<<dim3(24, 32), 256, 0, stream>>>(xb, wTa, nullptr, 0, flagp, nullptr, qkvb,
                                                     4096, 3072, 1024, 1024, 1024, 3072);
        attn_qk<<<512, 256, 0, stream>>>(qkvb, sph_dist, flagp, dots);
        attn_stats<<<1024, 256, 0, stream>>>(dots, attnb);
        attn_pv<<<512, 256, 0, stream>>>(attnb, qkvb, o_bf);
        gemm_nt<2><<<dim3(8, 32), 256, 0, stream>>>(o_bf, wTb, wo_b, l * 1024, flagp, xf, nullptr,
                                                    4096, 1024, 1024, 1024, 1024, 1024);
    }

    // final LN + expand head (bf16 into qkvb) + un-patchify (dtype per flag)
    ln_f32_to_bf16<<<4096, 256, 0, stream>>>(xf, trg, trb, 0, flagp, xb);
    transpose_k<<<dim3(96, 32), 256, 0, stream>>>(exp_w, 0, wTa, 1024, 3072, flagp);
    gemm_nt<1><<<dim3(24, 32), 256, 0, stream>>>(xb, wTa, exp_b, 0, flagp, nullptr, qkvb,
                                                 4096, 3072, 1024, 1024, 1024, 3072);
    out_ln_rearrange<<<4096, 256, 0, stream>>>(qkvb, og, ob, flagp, d_out);
}

// Round 6
// 2174.328 us; speedup vs baseline: 1.6735x; 1.6735x over previous
//
#include <hip/hip_runtime.h>
#include <stdint.h>

// ---------------------------------------------------------------------------
// SphereViT forward on gfx950.  Inputs/outputs fp32 (flag-sniffed, R5-verified
// flag=1 world).  Residual fp32 in ws; GEMMs bf16 MFMA 16x16x32.
// R6: gemm_nt gets (a) global_load_lds width-16 async staging (m97 pattern),
// (b) XCD-aware tile swizzle (lid%8=xcd, per-XCD RMxRN region) to make the
// staging loads L2-resident.  R5 counters: FETCH 101MB vs 14MB ideal = L2
// thrash across XCDs; MfmaUtil 6% = latency-bound.
// ---------------------------------------------------------------------------

typedef __attribute__((ext_vector_type(8))) short short8;   // 8 x bf16
typedef __attribute__((ext_vector_type(4))) float f32x4;    // MFMA C/D frag

#define EPS 1e-5f

__device__ __forceinline__ float b2f(ushort u) {
    union { uint32_t i; float f; } c; c.i = ((uint32_t)u) << 16; return c.f;
}
__device__ __forceinline__ ushort f2b(float f) {
    union { float f; uint32_t i; } c; c.f = f;
    uint32_t u = c.i;
    uint32_t r = (u + 0x7fffu + ((u >> 16) & 1u)) >> 16;   // RNE
    return (ushort)r;
}
__device__ __forceinline__ void async16(const ushort* g, ushort* l) {
    __builtin_amdgcn_global_load_lds(
        (const __attribute__((address_space(1))) uint32_t*)g,
        (__attribute__((address_space(3))) uint32_t*)l, 16, 0, 0);
}

// block-wide sum of (s, ss) for 256-thread blocks (4 waves)
__device__ __forceinline__ float2 block_sum2(float s, float ss, int tid) {
    #pragma unroll
    for (int o = 32; o; o >>= 1) { s += __shfl_xor(s, o); ss += __shfl_xor(ss, o); }
    __shared__ float ps[4], pss[4];
    int w = tid >> 6;
    if ((tid & 63) == 0) { ps[w] = s; pss[w] = ss; }
    __syncthreads();
    return make_float2(ps[0] + ps[1] + ps[2] + ps[3],
                       pss[0] + pss[1] + pss[2] + pss[3]);
}

// ---------------------------------------------------------------------------
// Exact dtype sniffer on the all-ones nl_ln1_g tensor (R5: flag=1, fp32).
// ---------------------------------------------------------------------------
__global__ void sniff_dtype(const uint32_t* __restrict__ ones, int* __restrict__ flag) {
    if (threadIdx.x == 0 && blockIdx.x == 0) {
        int c32 = 0, c16 = 0;
        for (int i = 0; i < 256; i++) {
            uint32_t w = ones[i];
            c32 += (w == 0x3F800000u);
            c16 += (w == 0x3F803F80u);
        }
        *flag = (c32 >= c16) ? 1 : 0;
    }
}

// ---------------------------------------------------------------------------
// NT GEMM: C[M,N] = A[M,K]*Bt[N,K]^T (+bias).  A,Bt bf16 K-contiguous.
// 128x128 tile, BK=32, 4 waves (2x2 of 64x64).  global_load_lds staging.
// XCD swizzle: lid%8 -> xcd; each XCD owns an RM x RN tile region so its
// 96/32 co-resident blocks share A/B panels in the 4 MiB per-XCD L2.
// MODE 0: store fp32 | 1: store bf16 | 2: fp32 +=
// ---------------------------------------------------------------------------
template <int MODE>
__global__ __launch_bounds__(256) void gemm_nt(
    const ushort* __restrict__ A, const ushort* __restrict__ Bt,
    const void* __restrict__ bias, int bias_off, const int* __restrict__ flagp,
    float* __restrict__ Cf, ushort* __restrict__ Cb,
    int M, int N, int K, int ldA, int ldB, int ldC, int RM, int RN)
{
    __shared__ ushort As[128 * 32];
    __shared__ ushort Bs[128 * 32];
    const int tid = threadIdx.x, lane = tid & 63, w = tid >> 6;

    // --- XCD-aware swizzle (bijective for any grid divisible into regions) ---
    int lid = blockIdx.y * gridDim.x + blockIdx.x;
    int xcd = lid & 7, slot = lid >> 3;
    int regions_n = gridDim.x / RN;           // regions along N
    int r_m = xcd / regions_n, r_n = xcd % regions_n;
    int tm = r_m * RM + slot / RN;
    int tn = r_n * RN + slot % RN;
    const int m0 = tm * 128, n0 = tn * 128;

    const int wr = (w >> 1) * 64, wc = (w & 1) * 64;
    const int m16 = lane & 15, quad = lane >> 4;

    f32x4 acc[4][4];
    #pragma unroll
    for (int i = 0; i < 4; i++)
        #pragma unroll
        for (int j = 0; j < 4; j++) acc[i][j] = (f32x4){0.f, 0.f, 0.f, 0.f};

    const int idx0 = (w * 2) * 64 + lane, idx1 = (w * 2 + 1) * 64 + lane;
    const int row0 = idx0 >> 2, ks0 = (idx0 & 3) * 8;
    const int row1 = idx1 >> 2, ks1 = (idx1 & 3) * 8;
    const ushort* a0 = A  + (size_t)(m0 + row0) * ldA + ks0;
    const ushort* a1 = A  + (size_t)(m0 + row1) * ldA + ks1;
    const ushort* b0 = Bt + (size_t)(n0 + row0) * ldB + ks0;
    const ushort* b1 = Bt + (size_t)(n0 + row1) * ldB + ks1;

    for (int k0 = 0; k0 < K; k0 += 32) {
        __syncthreads();                    // prev iter's LDS readers done
        async16(a0 + k0, As + (w * 2 + 0) * 512);
        async16(a1 + k0, As + (w * 2 + 1) * 512);
        async16(b0 + k0, Bs + (w * 2 + 0) * 512);
        async16(b1 + k0, Bs + (w * 2 + 1) * 512);
        __syncthreads();                    // compiler drains vmcnt before barrier
        short8 a[4], b[4];
        #pragma unroll
        for (int t = 0; t < 4; t++)
            a[t] = *(const short8*)(As + (wr + t * 16 + m16) * 32 + quad * 8);
        #pragma unroll
        for (int t = 0; t < 4; t++)
            b[t] = *(const short8*)(Bs + (wc + t * 16 + m16) * 32 + quad * 8);
        #pragma unroll
        for (int i = 0; i < 4; i++)
            #pragma unroll
            for (int j = 0; j < 4; j++)
                acc[i][j] = __builtin_amdgcn_mfma_f32_16x16x32_bf16(a[i], b[j], acc[i][j], 0, 0, 0);
    }

    float bvals[4] = {0.f, 0.f, 0.f, 0.f};
    if (bias) {
        if (*flagp) {
            #pragma unroll
            for (int j = 0; j < 4; j++)
                bvals[j] = ((const float*)bias)[bias_off + n0 + wc + j * 16 + m16];
        } else {
            #pragma unroll
            for (int j = 0; j < 4; j++)
                bvals[j] = b2f(((const ushort*)bias)[bias_off + n0 + wc + j * 16 + m16]);
        }
    }
    #pragma unroll
    for (int i = 0; i < 4; i++)
        #pragma unroll
        for (int j = 0; j < 4; j++)
            #pragma unroll
            for (int r = 0; r < 4; r++) {
                int row = m0 + wr + i * 16 + quad * 4 + r;
                int col = n0 + wc + j * 16 + m16;
                float v = acc[i][j][r] + bvals[j];
                if (MODE == 0)      Cf[(size_t)row * ldC + col] = v;
                else if (MODE == 1) Cb[(size_t)row * ldC + col] = f2b(v);
                else                Cf[(size_t)row * ldC + col] += v;
            }
}

// ---------------------------------------------------------------------------
// Transpose W[K,N] -> Wt[N,K] bf16, reading fp32 or bf16 source.
// ---------------------------------------------------------------------------
__global__ __launch_bounds__(256) void transpose_k(
    const void* __restrict__ W, size_t eoff, ushort* __restrict__ Wt,
    int K, int N, const int* __restrict__ flagp)
{
    __shared__ ushort t[32][33];
    int f32 = *flagp;
    int n0 = blockIdx.x * 32, k0 = blockIdx.y * 32;
    int tx = threadIdx.x & 31, ty = threadIdx.x >> 5;
    if (f32) {
        const float* Wf = (const float*)W + eoff;
        #pragma unroll
        for (int i = ty; i < 32; i += 8) t[i][tx] = f2b(Wf[(size_t)(k0 + i) * N + n0 + tx]);
    } else {
        const ushort* Wb = (const ushort*)W + eoff;
        #pragma unroll
        for (int i = ty; i < 32; i += 8) t[i][tx] = Wb[(size_t)(k0 + i) * N + n0 + tx];
    }
    __syncthreads();
    #pragma unroll
    for (int i = ty; i < 32; i += 8) Wt[(size_t)(n0 + i) * K + k0 + tx] = t[tx][i];
}

// Dtype-convert copy (8 elems/thread), for conv_w (already [N,K] layout).
__global__ __launch_bounds__(256) void convert_copy(
    const void* __restrict__ src, ushort* __restrict__ dst,
    const int* __restrict__ flagp)
{
    size_t i = ((size_t)blockIdx.x * 256 + threadIdx.x) * 8;
    if (*flagp) {
        const float* s = (const float*)src + i;
        ushort t[8];
        #pragma unroll
        for (int x = 0; x < 8; x++) t[x] = f2b(s[x]);
        *(uint4*)(dst + i) = *(uint4*)t;
    } else {
        *(uint4*)(dst + i) = *(const uint4*)((const ushort*)src + i);
    }
}

// ---------------------------------------------------------------------------
// Patch gather: img[b,c,256,512] -> A[(b,h,w)][(c,p,q)] bf16 (4096x3072)
// ---------------------------------------------------------------------------
__global__ __launch_bounds__(256) void patch_gather(
    const void* __restrict__ img, ushort* __restrict__ Ap,
    const int* __restrict__ flagp)
{
    int t = blockIdx.x * 256 + threadIdx.x;
    int qc = t & 3;
    int p  = (t >> 2) & 31;
    int c  = (t >> 7) % 3;
    int rest = t / 384;
    int wg = rest & 15;
    int hg = (rest >> 4) & 7;
    int b  = rest >> 7;
    size_t si = ((size_t)((b * 3 + c) * 256 + hg * 32 + p)) * 512 + wg * 32 + qc * 8;
    size_t di = ((size_t)((b * 8 + hg) * 16 + wg)) * 3072 + c * 1024 + p * 32 + qc * 8;
    if (*flagp) {
        const float* s = (const float*)img + si;
        ushort tmp[8];
        #pragma unroll
        for (int x = 0; x < 8; x++) tmp[x] = f2b(s[x]);
        *(uint4*)(Ap + di) = *(uint4*)tmp;
    } else {
        *(uint4*)(Ap + di) = *(const uint4*)((const ushort*)img + si);
    }
}

// ---------------------------------------------------------------------------
// LayerNorm over 1024 (fp32 in) -> bf16 out.  g/b dual-dtype, +elem offset.
// ---------------------------------------------------------------------------
__global__ __launch_bounds__(256) void ln_f32_to_bf16(
    const float* __restrict__ X, const void* __restrict__ g,
    const void* __restrict__ b, int goff, const int* __restrict__ flagp,
    ushort* __restrict__ Y)
{
    int row = blockIdx.x, tid = threadIdx.x;
    float4 v = ((const float4*)(X + (size_t)row * 1024))[tid];
    float s = v.x + v.y + v.z + v.w;
    float ss = v.x * v.x + v.y * v.y + v.z * v.z + v.w * v.w;
    float2 r = block_sum2(s, ss, tid);
    float mu = r.x * (1.f / 1024.f);
    float var = fmaxf(r.y * (1.f / 1024.f) - mu * mu, 0.f);
    float rs = rsqrtf(var + EPS);
    int c0 = tid * 4;
    float gv[4], bv[4];
    if (*flagp) {
        #pragma unroll
        for (int x = 0; x < 4; x++) { gv[x] = ((const float*)g)[goff + c0 + x]; bv[x] = ((const float*)b)[goff + c0 + x]; }
    } else {
        #pragma unroll
        for (int x = 0; x < 4; x++) { gv[x] = b2f(((const ushort*)g)[goff + c0 + x]); bv[x] = b2f(((const ushort*)b)[goff + c0 + x]); }
    }
    ushort4 o4;
    o4.x = f2b((v.x - mu) * rs * gv[0] + bv[0]);
    o4.y = f2b((v.y - mu) * rs * gv[1] + bv[1]);
    o4.z = f2b((v.z - mu) * rs * gv[2] + bv[2]);
    o4.w = f2b((v.w - mu) * rs * gv[3] + bv[3]);
    *(ushort4*)(Y + (size_t)row * 1024 + c0) = o4;
}

// LN over 1024 in-place fp32, then add spherical positional embedding
__global__ __launch_bounds__(256) void ln2_pos(
    float* __restrict__ X, const void* __restrict__ g, const void* __restrict__ b,
    const void* __restrict__ sph_pos, const void* __restrict__ pos_w,
    const void* __restrict__ pos_b, const int* __restrict__ flagp)
{
    int f32 = *flagp;
    int row = blockIdx.x, tid = threadIdx.x;
    float4 v = ((const float4*)(X + (size_t)row * 1024))[tid];
    float s = v.x + v.y + v.z + v.w;
    float ss = v.x * v.x + v.y * v.y + v.z * v.z + v.w * v.w;
    float2 r = block_sum2(s, ss, tid);
    float mu = r.x * (1.f / 1024.f);
    float var = fmaxf(r.y * (1.f / 1024.f) - mu * mu, 0.f);
    float rs = rsqrtf(var + EPS);
    int n = row & 127;
    int c0 = tid * 4;
    float s0, s1, gv[4], bv[4], w0[4], w1[4], pb[4];
    if (f32) {
        s0 = ((const float*)sph_pos)[n * 2 + 0]; s1 = ((const float*)sph_pos)[n * 2 + 1];
        #pragma unroll
        for (int x = 0; x < 4; x++) {
            gv[x] = ((const float*)g)[c0 + x];  bv[x] = ((const float*)b)[c0 + x];
            w0[x] = ((const float*)pos_w)[c0 + x]; w1[x] = ((const float*)pos_w)[1024 + c0 + x];
            pb[x] = ((const float*)pos_b)[c0 + x];
        }
    } else {
        s0 = b2f(((const ushort*)sph_pos)[n * 2 + 0]); s1 = b2f(((const ushort*)sph_pos)[n * 2 + 1]);
        #pragma unroll
        for (int x = 0; x < 4; x++) {
            gv[x] = b2f(((const ushort*)g)[c0 + x]);  bv[x] = b2f(((const ushort*)b)[c0 + x]);
            w0[x] = b2f(((const ushort*)pos_w)[c0 + x]); w1[x] = b2f(((const ushort*)pos_w)[1024 + c0 + x]);
            pb[x] = b2f(((const ushort*)pos_b)[c0 + x]);
        }
    }
    float4 o;
    o.x = (v.x - mu) * rs * gv[0] + bv[0] + s0 * w0[0] + s1 * w1[0] + pb[0];
    o.y = (v.y - mu) * rs * gv[1] + bv[1] + s0 * w0[1] + s1 * w1[1] + pb[1];
    o.z = (v.z - mu) * rs * gv[2] + bv[2] + s0 * w0[2] + s1 * w1[2] + pb[2];
    o.w = (v.w - mu) * rs * gv[3] + bv[3] + s0 * w0[3] + s1 * w1[3] + pb[3];
    *(float4*)(X + (size_t)row * 1024 + c0) = o;
}

// ---------------------------------------------------------------------------
// QK^T per (b,h): dots = scale*(q.k)*(1+sph_dist)  (fp32 out)
// ---------------------------------------------------------------------------
__global__ __launch_bounds__(256) void attn_qk(
    const ushort* __restrict__ qkv, const void* __restrict__ sph_dist,
    const int* __restrict__ flagp, float* __restrict__ dots)
{
    __shared__ ushort Qs[128 * 64];
    __shared__ ushort Ks[128 * 64];
    int bh = blockIdx.x, b = bh >> 4, h = bh & 15;
    int tid = threadIdx.x;
    {
        int i = tid >> 1, half = (tid & 1) * 32;
        const ushort* qsrc = qkv + (size_t)(b * 128 + i) * 3072 + h * 64 + half;
        const ushort* ksrc = qsrc + 1024;
        uint4* qdst = (uint4*)(Qs + i * 64 + half);
        uint4* kdst = (uint4*)(Ks + i * 64 + half);
        #pragma unroll
        for (int x = 0; x < 4; x++) { qdst[x] = ((const uint4*)qsrc)[x]; kdst[x] = ((const uint4*)ksrc)[x]; }
    }
    __syncthreads();
    int lane = tid & 63, w = tid >> 6, m16 = lane & 15, quad = lane >> 4;
    f32x4 acc[2][8];
    #pragma unroll
    for (int i = 0; i < 2; i++)
        #pragma unroll
        for (int j = 0; j < 8; j++) acc[i][j] = (f32x4){0.f, 0.f, 0.f, 0.f};
    #pragma unroll
    for (int kq = 0; kq < 2; kq++) {
        short8 a[2], bb[8];
        #pragma unroll
        for (int rt = 0; rt < 2; rt++)
            a[rt] = *(const short8*)(Qs + (w * 32 + rt * 16 + m16) * 64 + kq * 32 + quad * 8);
        #pragma unroll
        for (int ct = 0; ct < 8; ct++)
            bb[ct] = *(const short8*)(Ks + (ct * 16 + m16) * 64 + kq * 32 + quad * 8);
        #pragma unroll
        for (int rt = 0; rt < 2; rt++)
            #pragma unroll
            for (int ct = 0; ct < 8; ct++)
                acc[rt][ct] = __builtin_amdgcn_mfma_f32_16x16x32_bf16(a[rt], bb[ct], acc[rt][ct], 0, 0, 0);
    }
    const float scale = 0.125f;
    int f32 = *flagp;
    #pragma unroll
    for (int rt = 0; rt < 2; rt++)
        #pragma unroll
        for (int ct = 0; ct < 8; ct++)
            #pragma unroll
            for (int r = 0; r < 4; r++) {
                int i = w * 32 + rt * 16 + quad * 4 + r;
                int j = ct * 16 + m16;
                float sd = f32 ? ((const float*)sph_dist)[i * 128 + j]
                               : b2f(((const ushort*)sph_dist)[i * 128 + j]);
                dots[((size_t)bh * 128 + i) * 128 + j] = acc[rt][ct][r] * scale * (1.f + sd);
            }
}

// ---------------------------------------------------------------------------
// Cross-head standardization + softmax.  One wave per (b,i); lane j, j+64.
// ---------------------------------------------------------------------------
__global__ __launch_bounds__(256) void attn_stats(
    const float* __restrict__ dots, ushort* __restrict__ attn)
{
    int gi = blockIdx.x * 4 + (threadIdx.x >> 6);
    int lane = threadIdx.x & 63;
    int b = gi >> 7, i = gi & 127;
    float v0[16], v1[16];
    #pragma unroll
    for (int h = 0; h < 16; h++) {
        const float* p = dots + ((size_t)(b * 16 + h) * 128 + i) * 128;
        v0[h] = p[lane]; v1[h] = p[lane + 64];
    }
    float s0 = 0.f, s1 = 0.f;
    #pragma unroll
    for (int h = 0; h < 16; h++) { s0 += v0[h]; s1 += v1[h]; }
    float mu0 = s0 * (1.f / 16.f), mu1 = s1 * (1.f / 16.f);
    float q0 = 0.f, q1 = 0.f;
    #pragma unroll
    for (int h = 0; h < 16; h++) {
        float d0 = v0[h] - mu0, d1 = v1[h] - mu1;
        q0 += d0 * d0; q1 += d1 * d1;
    }
    float r0 = rsqrtf(fmaxf(q0 * (1.f / 15.f), 1e-20f));   // ddof=1
    float r1 = rsqrtf(fmaxf(q1 * (1.f / 15.f), 1e-20f));
    #pragma unroll
    for (int h = 0; h < 16; h++) { v0[h] = (v0[h] - mu0) * r0; v1[h] = (v1[h] - mu1) * r1; }
    #pragma unroll
    for (int h = 0; h < 16; h++) {
        float m = fmaxf(v0[h], v1[h]);
        #pragma unroll
        for (int o = 32; o; o >>= 1) m = fmaxf(m, __shfl_xor(m, o));
        float e0 = __expf(v0[h] - m), e1 = __expf(v1[h] - m);
        float s = e0 + e1;
        #pragma unroll
        for (int o = 32; o; o >>= 1) s += __shfl_xor(s, o);
        float inv = 1.f / s;
        ushort* op = attn + ((size_t)(b * 16 + h) * 128 + i) * 128;
        op[lane] = f2b(e0 * inv);
        op[lane + 64] = f2b(e1 * inv);
    }
}

// ---------------------------------------------------------------------------
// PV per (b,h): o[i,d] = sum_j attn[i,j]*v[j,d] -> token-major bf16
// ---------------------------------------------------------------------------
__global__ __launch_bounds__(256) void attn_pv(
    const ushort* __restrict__ attn, const ushort* __restrict__ qkv,
    ushort* __restrict__ o)
{
    __shared__ ushort Ps[128 * 128];
    __shared__ ushort Vt[64 * 128];
    int bh = blockIdx.x, b = bh >> 4, h = bh & 15;
    int tid = threadIdx.x;
    {
        int i = tid >> 1, jh = (tid & 1) * 64;
        const uint4* src = (const uint4*)(attn + ((size_t)bh * 128 + i) * 128 + jh);
        uint4* dst = (uint4*)(Ps + i * 128 + jh);
        #pragma unroll
        for (int x = 0; x < 8; x++) dst[x] = src[x];
    }
    {
        int j = tid >> 1, dh = (tid & 1) * 32;
        const ushort* src = qkv + (size_t)(b * 128 + j) * 3072 + 2048 + h * 64 + dh;
        ushort tmp[32];
        #pragma unroll
        for (int x = 0; x < 4; x++) *(uint4*)(tmp + x * 8) = ((const uint4*)src)[x];
        #pragma unroll
        for (int x = 0; x < 32; x++) Vt[(dh + x) * 128 + j] = tmp[x];
    }
    __syncthreads();
    int lane = tid & 63, w = tid >> 6, m16 = lane & 15, quad = lane >> 4;
    f32x4 acc[2][4];
    #pragma unroll
    for (int i = 0; i < 2; i++)
        #pragma unroll
        for (int j = 0; j < 4; j++) acc[i][j] = (f32x4){0.f, 0.f, 0.f, 0.f};
    #pragma unroll
    for (int kq = 0; kq < 4; kq++) {
        short8 a[2], bb[4];
        #pragma unroll
        for (int rt = 0; rt < 2; rt++)
            a[rt] = *(const short8*)(Ps + (w * 32 + rt * 16 + m16) * 128 + kq * 32 + quad * 8);
        #pragma unroll
        for (int ct = 0; ct < 4; ct++)
            bb[ct] = *(const short8*)(Vt + (ct * 16 + m16) * 128 + kq * 32 + quad * 8);
        #pragma unroll
        for (int rt = 0; rt < 2; rt++)
            #pragma unroll
            for (int ct = 0; ct < 4; ct++)
                acc[rt][ct] = __builtin_amdgcn_mfma_f32_16x16x32_bf16(a[rt], bb[ct], acc[rt][ct], 0, 0, 0);
    }
    #pragma unroll
    for (int rt = 0; rt < 2; rt++)
        #pragma unroll
        for (int ct = 0; ct < 4; ct++)
            #pragma unroll
            for (int r = 0; r < 4; r++) {
                int i = w * 32 + rt * 16 + quad * 4 + r;
                int d = ct * 16 + m16;
                o[(size_t)(b * 128 + i) * 1024 + h * 64 + d] = f2b(acc[rt][ct][r]);
            }
}

// ---------------------------------------------------------------------------
// Final LN over 3072 (bf16 in) + un-patchify; writes fp32 OR bf16 per flag.
// ---------------------------------------------------------------------------
__global__ __launch_bounds__(256) void out_ln_rearrange(
    const ushort* __restrict__ Y, const void* __restrict__ g,
    const void* __restrict__ bb, const int* __restrict__ flagp,
    void* __restrict__ out)
{
    __shared__ float rowbuf[3072];
    int f32 = *flagp;
    int r = blockIdx.x;
    int b = r >> 7, n = r & 127, hg = n >> 4, wg = n & 15;
    int tid = threadIdx.x;
    float s = 0.f, ss = 0.f;
    #pragma unroll
    for (int x = 0; x < 3; x++) {
        ushort4 u = *(const ushort4*)(Y + (size_t)r * 3072 + (size_t)(x * 256 + tid) * 4);
        float4 v = make_float4(b2f(u.x), b2f(u.y), b2f(u.z), b2f(u.w));
        *(float4*)(rowbuf + (x * 256 + tid) * 4) = v;
        s += v.x + v.y + v.z + v.w;
        ss += v.x * v.x + v.y * v.y + v.z * v.z + v.w * v.w;
    }
    float2 red = block_sum2(s, ss, tid);   // barrier makes rowbuf visible
    float mu = red.x * (1.f / 3072.f);
    float var = fmaxf(red.y * (1.f / 3072.f) - mu * mu, 0.f);
    float rs = rsqrtf(var + EPS);
    int p1 = tid >> 3, sj = tid & 7;
    #pragma unroll
    for (int c = 0; c < 3; c++) {
        float vals[4];
        #pragma unroll
        for (int x = 0; x < 4; x++) {
            int p2 = sj * 4 + x;
            int col = p1 * 96 + p2 * 3 + c;
            float gv, bv;
            if (f32) { gv = ((const float*)g)[col];  bv = ((const float*)bb)[col]; }
            else     { gv = b2f(((const ushort*)g)[col]); bv = b2f(((const ushort*)bb)[col]); }
            vals[x] = (rowbuf[col] - mu) * rs * gv + bv;
        }
        size_t di = (size_t)((b * 3 + c) * 256 + hg * 32 + p1) * 512 + wg * 32 + sj * 4;
        if (f32) {
            *(float4*)((float*)out + di) = make_float4(vals[0], vals[1], vals[2], vals[3]);
        } else {
            ushort4 o4;
            #pragma unroll
            for (int x = 0; x < 4; x++) ((ushort*)&o4)[x] = f2b(vals[x]);
            *(ushort4*)((ushort*)out + di) = o4;
        }
    }
}

// ---------------------------------------------------------------------------
// Host-side orchestration
// ---------------------------------------------------------------------------
extern "C" void kernel_launch(void* const* d_in, const int* in_sizes, int n_in,
                              void* d_out, int out_size, void* d_ws, size_t ws_size,
                              hipStream_t stream)
{
    const void* img      = d_in[0];
    const void* sph_pos  = d_in[1];
    const void* sph_dist = d_in[2];
    const void* conv_w   = d_in[3];
    const void* conv_b   = d_in[4];
    const void* nl1g     = d_in[5];
    const void* nl1b     = d_in[6];
    const void* nl_w     = d_in[7];
    const void* nl_b     = d_in[8];
    const void* nl2g     = d_in[9];
    const void* nl2b     = d_in[10];
    const void* pos_w    = d_in[11];
    const void* pos_b    = d_in[12];
    const void* ln_g     = d_in[13];
    const void* ln_b     = d_in[14];
    const void* wqkv     = d_in[15];
    const void* wo       = d_in[16];
    const void* wo_b     = d_in[17];
    const void* trg      = d_in[18];
    const void* trb      = d_in[19];
    const void* exp_w    = d_in[20];
    const void* exp_b    = d_in[21];
    const void* og       = d_in[22];
    const void* ob       = d_in[23];

    // --- workspace layout: 88 MiB + flag ---
    char* ws = (char*)d_ws;
    float*  xf    = (float*) (ws + 0);            // [0,16M)   fp32 residual [4096,1024]
    ushort* xb    = (ushort*)(ws + 16777216);     // [16,24M)  bf16 LN out [4096,1024]
    ushort* qkvb  = (ushort*)(ws + 25165824);     // [24,48M)  bf16 qkv / patch-mat / expand-out
    float*  dots  = (float*) (ws + 50331648);     // [48,80M)  fp32 dots [32,16,128,128]
    float*  y1    = (float*) (ws + 50331648);     //   overlay: fp32 patch-embed out (pre-loop)
    ushort* o_bf  = (ushort*)(ws + 50331648);     //   overlay: bf16 attn out (after dots dead)
    ushort* wTa   = (ushort*)(ws + 83886080);     // [80,86M)  weight^T [3072,1024]
    ushort* wTb   = (ushort*)(ws + 90177536);     // [86,88M)  weight^T [1024,1024]
    int*    flagp = (int*)   (ws + 92274688);     // dtype flag (1 = fp32 world)
    ushort* attnb = (ushort*)d_out;               // bf16 attn probs (d_out dead until final write)

    sniff_dtype<<<1, 64, 0, stream>>>((const uint32_t*)nl1g, flagp);

    // patch embedding (patch matrix staged in qkvb region)
    patch_gather<<<6144, 256, 0, stream>>>(img, qkvb, flagp);
    convert_copy<<<1536, 256, 0, stream>>>(conv_w, wTa, flagp);   // 1024x3072 -> bf16
    gemm_nt<0><<<dim3(8, 32), 256, 0, stream>>>(qkvb, wTa, conv_b, 0, flagp, y1, nullptr,
                                                4096, 1024, 3072, 3072, 3072, 1024, 4, 8);
    // norm_linear
    ln_f32_to_bf16<<<4096, 256, 0, stream>>>(y1, nl1g, nl1b, 0, flagp, xb);
    transpose_k<<<dim3(32, 32), 256, 0, stream>>>(nl_w, 0, wTb, 1024, 1024, flagp);
    gemm_nt<0><<<dim3(8, 32), 256, 0, stream>>>(xb, wTb, nl_b, 0, flagp, xf, nullptr,
                                                4096, 1024, 1024, 1024, 1024, 1024, 4, 8);
    ln2_pos<<<4096, 256, 0, stream>>>(xf, nl2g, nl2b, sph_pos, pos_w, pos_b, flagp);

    // transformer blocks
    for (int l = 0; l < 12; l++) {
        transpose_k<<<dim3(96, 32), 256, 0, stream>>>(wqkv, (size_t)l * 1024 * 3072, wTa, 1024, 3072, flagp);
        transpose_k<<<dim3(32, 32), 256, 0, stream>>>(wo, (size_t)l * 1024 * 1024, wTb, 1024, 1024, flagp);
        ln_f32_to_bf16<<<4096, 256, 0, stream>>>(xf, ln_g, ln_b, l * 1024, flagp, xb);
        gemm_nt<1><<<dim3(24, 32), 256, 0, stream>>>(xb, wTa, nullptr, 0, flagp, nullptr, qkvb,
                                                     4096, 3072, 1024, 1024, 1024, 3072, 8, 12);
        attn_qk<<<512, 256, 0, stream>>>(qkvb, sph_dist, flagp, dots);
        attn_stats<<<1024, 256, 0, stream>>>(dots, attnb);
        attn_pv<<<512, 256, 0, stream>>>(attnb, qkvb, o_bf);
        gemm_nt<2><<<dim3(8, 32), 256, 0, stream>>>(o_bf, wTb, wo_b, l * 1024, flagp, xf, nullptr,
                                                    4096, 1024, 1024, 1024, 1024, 1024, 4, 8);
    }

    // final LN + expand head (bf16 into qkvb) + un-patchify (dtype per flag)
    ln_f32_to_bf16<<<4096, 256, 0, stream>>>(xf, trg, trb, 0, flagp, xb);
    transpose_k<<<dim3(96, 32), 256, 0, stream>>>(exp_w, 0, wTa, 1024, 3072, flagp);
    gemm_nt<1><<<dim3(24, 32), 256, 0, stream>>>(xb, wTa, exp_b, 0, flagp, nullptr, qkvb,
                                                 4096, 3072, 1024, 1024, 1024, 3072, 8, 12);
    out_ln_rearrange<<<4096, 256, 0, stream>>>(qkvb, og, ob, flagp, d_out);
}